// Round 3
// baseline (622.024 us; speedup 1.0000x reference)
//
#include <hip/hip_runtime.h>
#include <math.h>

#define NODES_TOTAL 160000
#define NODES_REAL  5000
#define D 128
#define NEG 0.2f
#define WT_L 32768   // per-layer ushorts: hi 128*128 then lo 128*128

typedef unsigned short ushort_t;
typedef unsigned int uint_t;
typedef __attribute__((ext_vector_type(8))) __bf16 bf16x8;
typedef __attribute__((ext_vector_type(4))) float f32x4;
union BF8 { bf16x8 v; ushort_t u[8]; };

__device__ __forceinline__ void split2(float x, ushort_t& hi, ushort_t& lo) {
    unsigned u = __float_as_uint(x);
    hi = (ushort_t)(u >> 16);
    float hif = __uint_as_float(u & 0xffff0000u);
    lo = (ushort_t)(__float_as_uint(x - hif) >> 16);
}
// monotone float<->uint order-preserving map (for atomicMax over floats)
__device__ __forceinline__ uint_t encmax(float f) {
    uint_t b = __float_as_uint(f);
    return b ^ ((uint_t)((int)b >> 31) | 0x80000000u);
}
__device__ __forceinline__ float decmax(uint_t u) {
    uint_t b = (u & 0x80000000u) ? (u ^ 0x80000000u) : ~u;
    return __uint_as_float(b);
}

// ---------------- CSR build ----------------------------------------------------
__global__ void zero_kernel(int* counts, uint_t* gmaxu) {
    int i = blockIdx.x * blockDim.x + threadIdx.x;
    if (i < NODES_REAL) counts[i] = 0;
    if (i == 0) *gmaxu = 0u;
}

// fused hist + rank: atomic return value IS the edge's rank within its dst
__global__ void rank_kernel(const int* __restrict__ ei, int* __restrict__ counts,
                            ushort_t* __restrict__ rank16, int Eh) {
    int e = blockIdx.x * blockDim.x + threadIdx.x;
    if (e < Eh) {
        int d = ei[Eh + e];
        int r = atomicAdd(&counts[d], 1);
        rank16[e] = (ushort_t)r;
    }
}

__global__ void scan_kernel(const int* __restrict__ counts, int* __restrict__ offs) {
    __shared__ int sd[1024];
    int t = threadIdx.x;
    int pre[5]; int sum = 0;
    #pragma unroll
    for (int u = 0; u < 5; ++u) {
        int idx = t * 5 + u;
        int c = (idx < NODES_REAL) ? counts[idx] : 0;
        pre[u] = sum; sum += c;
    }
    sd[t] = sum;
    __syncthreads();
    int run = sum;
    for (int o = 1; o < 1024; o <<= 1) {
        int v = (t >= o) ? sd[t - o] : 0;
        __syncthreads();
        sd[t] += v;
        __syncthreads();
    }
    int excl = sd[t] - run;
    #pragma unroll
    for (int u = 0; u < 5; ++u) {
        int idx = t * 5 + u;
        if (idx < NODES_REAL) offs[idx] = excl + pre[u];
    }
    if (t == 1023) offs[NODES_REAL] = excl + run;
}

// deterministic scatter: no atomics, fire-and-forget stores
__global__ void scatter_det(const int* __restrict__ ei, const int* __restrict__ offs,
                            const ushort_t* __restrict__ rank16, int* __restrict__ esrc,
                            int Eh) {
    int e = blockIdx.x * blockDim.x + threadIdx.x;
    if (e < Eh) {
        int s = ei[e];
        int d = ei[Eh + e];
        esrc[offs[d] + (int)rank16[e]] = s;
    }
}

// ---------------- W split+transpose: Wt[l] = [hi: [n][128]] [lo: [n][128]] -----
__global__ void wsplit_kernel(const float* __restrict__ Ws, ushort_t* __restrict__ Wt) {
    int l  = blockIdx.x >> 3;
    int n  = (blockIdx.x & 7) * 16 + (threadIdx.x >> 4);
    int k0 = (threadIdx.x & 15) * 8;
    const float* src = Ws + (size_t)l * D * D;
    union { ushort_t u[8]; uint4 v; } hi, lo;
    #pragma unroll
    for (int j = 0; j < 8; ++j) split2(src[(size_t)(k0 + j) * D + n], hi.u[j], lo.u[j]);
    ushort_t* dhi = Wt + (size_t)l * WT_L + n * D + k0;
    *(uint4*)dhi = hi.v;
    *(uint4*)(dhi + 128 * D) = lo.v;
}

// ---------------- fused 3-layer MLP for rows [5000,160000) ---------------------
// These rows have only self-loops: out = relu(h@W + b) chained 3x, no edges.
// Block: 256 thr = 4 waves x 32 rows. B-frags from global (L2-cached Wt).
// C->A layout transform between layers via per-wave private LDS scratch (no barriers).
__global__ __launch_bounds__(256, 2)
void mlp3_kernel(const float* __restrict__ x, const ushort_t* __restrict__ Wt,
                 const float* __restrict__ bs, float* __restrict__ out) {
    __shared__ float scr[4][2][16][132];   // [wave][rt][row][col+pad] = 67.6 KB
    int tid = threadIdx.x;
    int w = tid >> 6, lane = tid & 63, q = lane >> 4, m16 = lane & 15;
    int row0 = NODES_REAL + blockIdx.x * 128 + w * 32;
    f32x4 acc[2][8];
    #pragma unroll
    for (int l = 0; l < 3; ++l) {
        const ushort_t* Wl = Wt + l * WT_L;
        #pragma unroll
        for (int rt = 0; rt < 2; ++rt)
            #pragma unroll
            for (int ct = 0; ct < 8; ++ct) acc[rt][ct] = (f32x4){0.f, 0.f, 0.f, 0.f};
        #pragma unroll
        for (int kc = 0; kc < 4; ++kc) {
            BF8 ahi[2], alo[2];
            #pragma unroll
            for (int rt = 0; rt < 2; ++rt) {
                float xv[8];
                if (l == 0) {
                    int r = row0 + rt * 16 + m16;
                    if (r > NODES_TOTAL - 1) r = NODES_TOTAL - 1;   // tail clamp
                    const float* gp = x + (size_t)r * D + kc * 32 + q * 8;
                    float4 v0 = *(const float4*)gp, v1 = *(const float4*)(gp + 4);
                    xv[0]=v0.x; xv[1]=v0.y; xv[2]=v0.z; xv[3]=v0.w;
                    xv[4]=v1.x; xv[5]=v1.y; xv[6]=v1.z; xv[7]=v1.w;
                } else {
                    const float* sp = &scr[w][rt][m16][kc * 32 + q * 8];
                    float4 v0 = *(const float4*)sp, v1 = *(const float4*)(sp + 4);
                    xv[0]=v0.x; xv[1]=v0.y; xv[2]=v0.z; xv[3]=v0.w;
                    xv[4]=v1.x; xv[5]=v1.y; xv[6]=v1.z; xv[7]=v1.w;
                }
                #pragma unroll
                for (int j = 0; j < 8; ++j) split2(xv[j], ahi[rt].u[j], alo[rt].u[j]);
            }
            #pragma unroll
            for (int ct = 0; ct < 8; ++ct) {
                const ushort_t* bp = Wl + (ct * 16 + m16) * D + kc * 32 + q * 8;
                bf16x8 bhi = *(const bf16x8*)bp;
                bf16x8 blo = *(const bf16x8*)(bp + 128 * D);
                #pragma unroll
                for (int rt = 0; rt < 2; ++rt) {
                    acc[rt][ct] = __builtin_amdgcn_mfma_f32_16x16x32_bf16(ahi[rt].v, bhi, acc[rt][ct], 0, 0, 0);
                    acc[rt][ct] = __builtin_amdgcn_mfma_f32_16x16x32_bf16(ahi[rt].v, blo, acc[rt][ct], 0, 0, 0);
                    acc[rt][ct] = __builtin_amdgcn_mfma_f32_16x16x32_bf16(alo[rt].v, bhi, acc[rt][ct], 0, 0, 0);
                }
            }
        }
        float bv[8];
        #pragma unroll
        for (int ct = 0; ct < 8; ++ct) bv[ct] = bs[l * D + ct * 16 + m16];
        if (l < 2) {
            // relu(h2+b) -> per-wave scratch (C-layout in, A-layout read next layer)
            #pragma unroll
            for (int rt = 0; rt < 2; ++rt)
                #pragma unroll
                for (int ct = 0; ct < 8; ++ct)
                    #pragma unroll
                    for (int reg = 0; reg < 4; ++reg)
                        scr[w][rt][q * 4 + reg][ct * 16 + m16] =
                            fmaxf(acc[rt][ct][reg] + bv[ct], 0.f);
            // no barrier: scratch is wave-private; compiler orders via lgkmcnt
        } else {
            #pragma unroll
            for (int rt = 0; rt < 2; ++rt)
                #pragma unroll
                for (int reg = 0; reg < 4; ++reg) {
                    int grow = row0 + rt * 16 + q * 4 + reg;
                    if (grow < NODES_TOTAL) {
                        #pragma unroll
                        for (int ct = 0; ct < 8; ++ct)
                            out[(size_t)grow * D + ct * 16 + m16] =
                                fmaxf(acc[rt][ct][reg] + bv[ct], 0.f);
                    }
                }
        }
    }
}

// ---------------- small GEMM (rows<5000) + fused scores + global max -----------
__global__ __launch_bounds__(256)
void gsmall_kernel(const float* __restrict__ hin, const ushort_t* __restrict__ Wl,
                   const float* __restrict__ a_s, const float* __restrict__ a_d,
                   float* __restrict__ h2, float* __restrict__ sv, float* __restrict__ dv,
                   uint_t* __restrict__ gmaxu) {
    int tid = threadIdx.x;
    int w = tid >> 6, lane = tid & 63, q = lane >> 4, m16 = lane & 15;
    int row0 = blockIdx.x * 128 + w * 32;
    f32x4 acc[2][8];
    #pragma unroll
    for (int rt = 0; rt < 2; ++rt)
        #pragma unroll
        for (int ct = 0; ct < 8; ++ct) acc[rt][ct] = (f32x4){0.f, 0.f, 0.f, 0.f};
    #pragma unroll
    for (int kc = 0; kc < 4; ++kc) {
        BF8 ahi[2], alo[2];
        #pragma unroll
        for (int rt = 0; rt < 2; ++rt) {
            int r = row0 + rt * 16 + m16;
            if (r > NODES_REAL - 1) r = NODES_REAL - 1;
            const float* gp = hin + (size_t)r * D + kc * 32 + q * 8;
            float4 v0 = *(const float4*)gp, v1 = *(const float4*)(gp + 4);
            float xv[8] = {v0.x, v0.y, v0.z, v0.w, v1.x, v1.y, v1.z, v1.w};
            #pragma unroll
            for (int j = 0; j < 8; ++j) split2(xv[j], ahi[rt].u[j], alo[rt].u[j]);
        }
        #pragma unroll
        for (int ct = 0; ct < 8; ++ct) {
            const ushort_t* bp = Wl + (ct * 16 + m16) * D + kc * 32 + q * 8;
            bf16x8 bhi = *(const bf16x8*)bp;
            bf16x8 blo = *(const bf16x8*)(bp + 128 * D);
            #pragma unroll
            for (int rt = 0; rt < 2; ++rt) {
                acc[rt][ct] = __builtin_amdgcn_mfma_f32_16x16x32_bf16(ahi[rt].v, bhi, acc[rt][ct], 0, 0, 0);
                acc[rt][ct] = __builtin_amdgcn_mfma_f32_16x16x32_bf16(ahi[rt].v, blo, acc[rt][ct], 0, 0, 0);
                acc[rt][ct] = __builtin_amdgcn_mfma_f32_16x16x32_bf16(alo[rt].v, bhi, acc[rt][ct], 0, 0, 0);
            }
        }
    }
    // h2 stores (raw, no bias/relu)
    #pragma unroll
    for (int rt = 0; rt < 2; ++rt)
        #pragma unroll
        for (int reg = 0; reg < 4; ++reg) {
            int grow = row0 + rt * 16 + q * 4 + reg;
            if (grow < NODES_REAL) {
                #pragma unroll
                for (int ct = 0; ct < 8; ++ct)
                    h2[(size_t)grow * D + ct * 16 + m16] = acc[rt][ct][reg];
            }
        }
    // fused scores: sv = h2 . a_s, dv = h2 . a_d (reduce over 16 m16-lanes)
    float asv[8], adv[8];
    #pragma unroll
    for (int ct = 0; ct < 8; ++ct) { asv[ct] = a_s[ct * 16 + m16]; adv[ct] = a_d[ct * 16 + m16]; }
    #pragma unroll
    for (int rt = 0; rt < 2; ++rt)
        #pragma unroll
        for (int reg = 0; reg < 4; ++reg) {
            float ps = 0.f, pd = 0.f;
            #pragma unroll
            for (int ct = 0; ct < 8; ++ct) {
                float v = acc[rt][ct][reg];
                ps += v * asv[ct]; pd += v * adv[ct];
            }
            #pragma unroll
            for (int o = 1; o < 16; o <<= 1) { ps += __shfl_xor(ps, o); pd += __shfl_xor(pd, o); }
            int grow = row0 + rt * 16 + q * 4 + reg;
            if (m16 == 0 && grow < NODES_REAL) {
                sv[grow] = ps; dv[grow] = pd;
                atomicMax(gmaxu, encmax(ps));
            }
        }
}

// ---------------- aggregation: one wave per dst, global-bound softmax ----------
__global__ __launch_bounds__(256)
void agg_kernel(const float* __restrict__ h2, const float* __restrict__ sv,
                const float* __restrict__ dv, const int* __restrict__ offs,
                const int* __restrict__ esrc, const float* __restrict__ bias,
                float* __restrict__ out, const uint_t* __restrict__ gmaxu) {
    int w = threadIdx.x >> 6, lane = threadIdx.x & 63;
    int i = blockIdx.x * 4 + w;
    int start = offs[i], end = offs[i + 1];
    float d_i = dv[i];
    // m-hat >= every incoming score (leaky_relu monotone) -> exact softmax shift
    float gm = decmax(*gmaxu) + d_i;
    float m = gm > 0.f ? gm : NEG * gm;
    float ax = 0.f, ay = 0.f, exs = 0.f;
    for (int base = start; base < end; base += 64) {
        int cnt = min(64, end - base);
        int srci = (lane < cnt) ? esrc[base + lane] : 0;
        float sc = sv[srci] + d_i;
        sc = sc > 0.f ? sc : NEG * sc;
        float ex = (lane < cnt) ? __expf(sc - m) : 0.f;
        exs += ex;
        if (cnt == 64) {
            #pragma unroll 4
            for (int j = 0; j < 64; ++j) {
                int   src = __shfl(srci, j);
                float e   = __shfl(ex, j);
                float2 hv = *(const float2*)&h2[(size_t)src * D + 2 * lane];
                ax += e * hv.x; ay += e * hv.y;
            }
        } else {
            for (int j = 0; j < cnt; ++j) {
                int   src = __shfl(srci, j);
                float e   = __shfl(ex, j);
                float2 hv = *(const float2*)&h2[(size_t)src * D + 2 * lane];
                ax += e * hv.x; ay += e * hv.y;
            }
        }
    }
    // self loop
    float scf = sv[i] + d_i; scf = scf > 0.f ? scf : NEG * scf;
    float exf = __expf(scf - m);
    float2 hv = *(const float2*)&h2[(size_t)i * D + 2 * lane];
    ax += exf * hv.x; ay += exf * hv.y;
    #pragma unroll
    for (int o = 1; o < 64; o <<= 1) exs += __shfl_xor(exs, o);
    float rd = 1.f / (exs + exf);
    float2 b2 = *(const float2*)&bias[2 * lane];
    float2 o2 = make_float2(fmaxf(ax * rd + b2.x, 0.f), fmaxf(ay * rd + b2.y, 0.f));
    *(float2*)&out[(size_t)i * D + 2 * lane] = o2;
}

// ---------------- launcher -----------------------------------------------------
extern "C" void kernel_launch(void* const* d_in, const int* in_sizes, int n_in,
                              void* d_out, int out_size, void* d_ws, size_t ws_size,
                              hipStream_t stream) {
    const float* x   = (const float*)d_in[0];
    const int*   ei  = (const int*)d_in[1];
    const float* Ws  = (const float*)d_in[2];
    const float* as_ = (const float*)d_in[3];
    const float* ad_ = (const float*)d_in[4];
    const float* bs  = (const float*)d_in[5];
    float* out = (float*)d_out;
    int Eh = in_sizes[1] / 2;                    // 1,280,000

    char* ws = (char*)d_ws;
    float*    h2     = (float*)ws;                        // 2,560,000
    float*    bufS   = (float*)(ws + 2560000);            // 2,560,000
    float*    sv     = (float*)(ws + 5120000);            //    20,000
    float*    dv     = (float*)(ws + 5140000);            //    20,000
    int*      counts = (int*)  (ws + 5160000);            //    20,000
    int*      offs   = (int*)  (ws + 5180000);            //    20,004
    ushort_t* rank16 = (ushort_t*)(ws + 5200016);         // 2,560,000
    int*      esrc   = (int*)  (ws + 7760016);            // 5,120,000
    ushort_t* Wt     = (ushort_t*)(ws + 12880016);        //   196,608
    uint_t*   gmaxu  = (uint_t*)(ws + 13076624);          //         4

    // CSR build (layer-invariant) + W split
    zero_kernel<<<(NODES_REAL + 255) / 256, 256, 0, stream>>>(counts, gmaxu);
    rank_kernel<<<(Eh + 255) / 256, 256, 0, stream>>>(ei, counts, rank16, Eh);
    scan_kernel<<<1, 1024, 0, stream>>>(counts, offs);
    scatter_det<<<(Eh + 255) / 256, 256, 0, stream>>>(ei, offs, rank16, esrc, Eh);
    wsplit_kernel<<<24, 256, 0, stream>>>(Ws, Wt);

    // rows >= 5000: pure 3-layer MLP chain, single pass over HBM
    mlp3_kernel<<<(NODES_TOTAL - NODES_REAL + 127) / 128, 256, 0, stream>>>(x, Wt, bs, out);

    // rows < 5000: per-layer GAT pipeline
    for (int l = 0; l < 3; ++l) {
        const float* hin = (l == 0) ? x : bufS;
        float* hout = (l == 2) ? out : bufS;
        gsmall_kernel<<<(NODES_REAL + 127) / 128, 256, 0, stream>>>(
            hin, Wt + (size_t)l * WT_L, as_ + l * D, ad_ + l * D, h2, sv, dv, gmaxu);
        agg_kernel<<<(NODES_REAL + 3) / 4, 256, 0, stream>>>(
            h2, sv, dv, offs, esrc, bs + l * D, hout, gmaxu);
    }
}

// Round 4
// 515.104 us; speedup vs baseline: 1.2076x; 1.2076x over previous
//
#include <hip/hip_runtime.h>
#include <math.h>

#define NODES_TOTAL 160000
#define NODES_REAL  5000
#define D 128
#define NEG 0.2f
#define KP 136                // padded k-pitch (ushorts) -> uniform-8 banks for ds_read_b128
#define HL (128 * KP)         // ushorts per hi (or lo) block = 17408
#define WT_L (2 * HL)         // ushorts per layer (hi + lo)  = 34816

typedef unsigned short ushort_t;
typedef unsigned int uint_t;
typedef __attribute__((ext_vector_type(8))) __bf16 bf16x8;
typedef __attribute__((ext_vector_type(4))) float f32x4;
union BF8 { bf16x8 v; ushort_t u[8]; };

__device__ __forceinline__ void split2(float x, ushort_t& hi, ushort_t& lo) {
    unsigned u = __float_as_uint(x);
    hi = (ushort_t)(u >> 16);
    float hif = __uint_as_float(u & 0xffff0000u);
    lo = (ushort_t)(__float_as_uint(x - hif) >> 16);
}
__device__ __forceinline__ uint_t encmax(float f) {
    uint_t b = __float_as_uint(f);
    return b ^ ((uint_t)((int)b >> 31) | 0x80000000u);
}
__device__ __forceinline__ float decmax(uint_t u) {
    uint_t b = (u & 0x80000000u) ? (u ^ 0x80000000u) : ~u;
    return __uint_as_float(b);
}

// ---------------- CSR build ----------------------------------------------------
__global__ void zero_kernel(int* counts, uint_t* gmaxu) {
    int i = blockIdx.x * blockDim.x + threadIdx.x;
    if (i < NODES_REAL) counts[i] = 0;
    if (i < 3) gmaxu[i] = 0u;
}

__global__ void rank_kernel(const int* __restrict__ ei, int* __restrict__ counts,
                            ushort_t* __restrict__ rank16, int Eh) {
    int e = blockIdx.x * blockDim.x + threadIdx.x;
    if (e < Eh) {
        int d = ei[Eh + e];
        int r = atomicAdd(&counts[d], 1);
        rank16[e] = (ushort_t)r;
    }
}

__global__ void scan_kernel(const int* __restrict__ counts, int* __restrict__ offs) {
    __shared__ int sd[1024];
    int t = threadIdx.x;
    int pre[5]; int sum = 0;
    #pragma unroll
    for (int u = 0; u < 5; ++u) {
        int idx = t * 5 + u;
        int c = (idx < NODES_REAL) ? counts[idx] : 0;
        pre[u] = sum; sum += c;
    }
    sd[t] = sum;
    __syncthreads();
    int run = sum;
    for (int o = 1; o < 1024; o <<= 1) {
        int v = (t >= o) ? sd[t - o] : 0;
        __syncthreads();
        sd[t] += v;
        __syncthreads();
    }
    int excl = sd[t] - run;
    #pragma unroll
    for (int u = 0; u < 5; ++u) {
        int idx = t * 5 + u;
        if (idx < NODES_REAL) offs[idx] = excl + pre[u];
    }
    if (t == 1023) offs[NODES_REAL] = excl + run;
}

// deterministic scatter, u16 payload (src < 5000)
__global__ void scatter_det(const int* __restrict__ ei, const int* __restrict__ offs,
                            const ushort_t* __restrict__ rank16, ushort_t* __restrict__ esrc,
                            int Eh) {
    int e = blockIdx.x * blockDim.x + threadIdx.x;
    if (e < Eh) {
        int s = ei[e];
        int d = ei[Eh + e];
        esrc[offs[d] + (int)rank16[e]] = (ushort_t)s;
    }
}

// ---------------- W split+transpose into padded layout [n][KP] hi then lo ------
__global__ void wsplit_kernel(const float* __restrict__ Ws, ushort_t* __restrict__ Wt) {
    int l  = blockIdx.x >> 3;
    int n  = (blockIdx.x & 7) * 16 + (threadIdx.x >> 4);
    int k0 = (threadIdx.x & 15) * 8;
    const float* src = Ws + (size_t)l * D * D;
    union { ushort_t u[8]; uint4 v; } hi, lo;
    #pragma unroll
    for (int j = 0; j < 8; ++j) split2(src[(size_t)(k0 + j) * D + n], hi.u[j], lo.u[j]);
    ushort_t* dhi = Wt + (size_t)l * WT_L + n * KP + k0;
    *(uint4*)dhi = hi.v;
    *(uint4*)(dhi + HL) = lo.v;
}

// ---------------- fused 3-layer MLP for rows [5000,160000) ---------------------
// W in LDS (staged per layer, 69.6KB), per-wave fp32 scratch for the C->A
// inter-layer transform (67.6KB). 137KB LDS -> 1 block/CU, 4 waves (1/SIMD).
__global__ __launch_bounds__(256)
void mlp3_kernel(const float* __restrict__ x, const ushort_t* __restrict__ Wt,
                 const float* __restrict__ bs, float* __restrict__ out) {
    __shared__ ushort_t Wl[WT_L];          // 69632 B
    __shared__ float scr[4][2][16][132];   // 67584 B
    int tid = threadIdx.x;
    int w = tid >> 6, lane = tid & 63, q = lane >> 4, m16 = lane & 15;
    int row0 = NODES_REAL + blockIdx.x * 128 + w * 32;

    // prefetch layer-0 A tiles into registers (hide HBM latency under W staging)
    float4 xa[2][4][2];
    #pragma unroll
    for (int rt = 0; rt < 2; ++rt) {
        int r = row0 + rt * 16 + m16;
        if (r > NODES_TOTAL - 1) r = NODES_TOTAL - 1;
        #pragma unroll
        for (int kc = 0; kc < 4; ++kc) {
            const float* gp = x + (size_t)r * D + kc * 32 + q * 8;
            xa[rt][kc][0] = *(const float4*)gp;
            xa[rt][kc][1] = *(const float4*)(gp + 4);
        }
    }

    f32x4 acc[2][8];
    #pragma unroll
    for (int l = 0; l < 3; ++l) {
        __syncthreads();   // prior layer's B-reads done before overwriting Wl
        {
            const uint4* gw = (const uint4*)(Wt + (size_t)l * WT_L);
            uint4* lw = (uint4*)Wl;
            #pragma unroll
            for (int r = 0; r < 17; ++r) lw[r * 256 + tid] = gw[r * 256 + tid];
        }
        __syncthreads();

        #pragma unroll
        for (int rt = 0; rt < 2; ++rt)
            #pragma unroll
            for (int ct = 0; ct < 8; ++ct) acc[rt][ct] = (f32x4){0.f, 0.f, 0.f, 0.f};

        #pragma unroll
        for (int kc = 0; kc < 4; ++kc) {
            BF8 ahi[2], alo[2];
            #pragma unroll
            for (int rt = 0; rt < 2; ++rt) {
                float xv[8];
                if (l == 0) {
                    float4 v0 = xa[rt][kc][0], v1 = xa[rt][kc][1];
                    xv[0]=v0.x; xv[1]=v0.y; xv[2]=v0.z; xv[3]=v0.w;
                    xv[4]=v1.x; xv[5]=v1.y; xv[6]=v1.z; xv[7]=v1.w;
                } else {
                    const float* sp = &scr[w][rt][m16][kc * 32 + q * 8];
                    float4 v0 = *(const float4*)sp, v1 = *(const float4*)(sp + 4);
                    xv[0]=v0.x; xv[1]=v0.y; xv[2]=v0.z; xv[3]=v0.w;
                    xv[4]=v1.x; xv[5]=v1.y; xv[6]=v1.z; xv[7]=v1.w;
                }
                #pragma unroll
                for (int j = 0; j < 8; ++j) split2(xv[j], ahi[rt].u[j], alo[rt].u[j]);
            }
            #pragma unroll
            for (int ct = 0; ct < 8; ++ct) {
                const ushort_t* bp = Wl + (ct * 16 + m16) * KP + kc * 32 + q * 8;
                bf16x8 bhi = *(const bf16x8*)bp;
                bf16x8 blo = *(const bf16x8*)(bp + HL);
                #pragma unroll
                for (int rt = 0; rt < 2; ++rt) {
                    acc[rt][ct] = __builtin_amdgcn_mfma_f32_16x16x32_bf16(ahi[rt].v, bhi, acc[rt][ct], 0, 0, 0);
                    acc[rt][ct] = __builtin_amdgcn_mfma_f32_16x16x32_bf16(ahi[rt].v, blo, acc[rt][ct], 0, 0, 0);
                    acc[rt][ct] = __builtin_amdgcn_mfma_f32_16x16x32_bf16(alo[rt].v, bhi, acc[rt][ct], 0, 0, 0);
                }
            }
        }
        // relu(h2 + b) -> per-wave scratch (C-layout in; A-layout read next layer,
        // linear read for the final store). Wave-private: no barrier needed.
        float bv[8];
        #pragma unroll
        for (int ct = 0; ct < 8; ++ct) bv[ct] = bs[l * D + ct * 16 + m16];
        #pragma unroll
        for (int rt = 0; rt < 2; ++rt)
            #pragma unroll
            for (int ct = 0; ct < 8; ++ct)
                #pragma unroll
                for (int reg = 0; reg < 4; ++reg)
                    scr[w][rt][q * 4 + reg][ct * 16 + m16] =
                        fmaxf(acc[rt][ct][reg] + bv[ct], 0.f);
    }
    // coalesced epilogue: wave streams its 32 rows x 128 cols from scr,
    // consecutive lanes -> consecutive 16B -> 1KB per store instruction.
    #pragma unroll
    for (int i = 0; i < 16; ++i) {
        int rowl = i * 2 + (lane >> 5);          // 0..31
        int rt = rowl >> 4, r16 = rowl & 15;
        int grow = row0 + rowl;
        float4 v = *(const float4*)&scr[w][rt][r16][(lane & 31) * 4];
        if (grow < NODES_TOTAL)
            *(float4*)&out[(size_t)grow * D + (lane & 31) * 4] = v;
    }
}

// ---------------- small GEMM (rows<5000) + fused scores + per-layer max --------
__global__ __launch_bounds__(256)
void gsmall_kernel(const float* __restrict__ hin, const ushort_t* __restrict__ Wlg,
                   const float* __restrict__ a_s, const float* __restrict__ a_d,
                   float* __restrict__ h2, float* __restrict__ sv, float* __restrict__ dv,
                   uint_t* __restrict__ gmaxu) {
    __shared__ ushort_t Wl[WT_L];
    int tid = threadIdx.x;
    {
        const uint4* gw = (const uint4*)Wlg;
        uint4* lw = (uint4*)Wl;
        #pragma unroll
        for (int r = 0; r < 17; ++r) lw[r * 256 + tid] = gw[r * 256 + tid];
    }
    int w = tid >> 6, lane = tid & 63, q = lane >> 4, m16 = lane & 15;
    int row0 = blockIdx.x * 128 + w * 32;
    f32x4 acc[2][8];
    #pragma unroll
    for (int rt = 0; rt < 2; ++rt)
        #pragma unroll
        for (int ct = 0; ct < 8; ++ct) acc[rt][ct] = (f32x4){0.f, 0.f, 0.f, 0.f};
    // prefetch A while W stages
    float4 xa[2][4][2];
    #pragma unroll
    for (int rt = 0; rt < 2; ++rt) {
        int r = row0 + rt * 16 + m16;
        if (r > NODES_REAL - 1) r = NODES_REAL - 1;
        #pragma unroll
        for (int kc = 0; kc < 4; ++kc) {
            const float* gp = hin + (size_t)r * D + kc * 32 + q * 8;
            xa[rt][kc][0] = *(const float4*)gp;
            xa[rt][kc][1] = *(const float4*)(gp + 4);
        }
    }
    __syncthreads();
    #pragma unroll
    for (int kc = 0; kc < 4; ++kc) {
        BF8 ahi[2], alo[2];
        #pragma unroll
        for (int rt = 0; rt < 2; ++rt) {
            float4 v0 = xa[rt][kc][0], v1 = xa[rt][kc][1];
            float xv[8] = {v0.x, v0.y, v0.z, v0.w, v1.x, v1.y, v1.z, v1.w};
            #pragma unroll
            for (int j = 0; j < 8; ++j) split2(xv[j], ahi[rt].u[j], alo[rt].u[j]);
        }
        #pragma unroll
        for (int ct = 0; ct < 8; ++ct) {
            const ushort_t* bp = Wl + (ct * 16 + m16) * KP + kc * 32 + q * 8;
            bf16x8 bhi = *(const bf16x8*)bp;
            bf16x8 blo = *(const bf16x8*)(bp + HL);
            #pragma unroll
            for (int rt = 0; rt < 2; ++rt) {
                acc[rt][ct] = __builtin_amdgcn_mfma_f32_16x16x32_bf16(ahi[rt].v, bhi, acc[rt][ct], 0, 0, 0);
                acc[rt][ct] = __builtin_amdgcn_mfma_f32_16x16x32_bf16(ahi[rt].v, blo, acc[rt][ct], 0, 0, 0);
                acc[rt][ct] = __builtin_amdgcn_mfma_f32_16x16x32_bf16(alo[rt].v, bhi, acc[rt][ct], 0, 0, 0);
            }
        }
    }
    #pragma unroll
    for (int rt = 0; rt < 2; ++rt)
        #pragma unroll
        for (int reg = 0; reg < 4; ++reg) {
            int grow = row0 + rt * 16 + q * 4 + reg;
            if (grow < NODES_REAL) {
                #pragma unroll
                for (int ct = 0; ct < 8; ++ct)
                    h2[(size_t)grow * D + ct * 16 + m16] = acc[rt][ct][reg];
            }
        }
    float asv[8], adv[8];
    #pragma unroll
    for (int ct = 0; ct < 8; ++ct) { asv[ct] = a_s[ct * 16 + m16]; adv[ct] = a_d[ct * 16 + m16]; }
    #pragma unroll
    for (int rt = 0; rt < 2; ++rt)
        #pragma unroll
        for (int reg = 0; reg < 4; ++reg) {
            float ps = 0.f, pd = 0.f;
            #pragma unroll
            for (int ct = 0; ct < 8; ++ct) {
                float v = acc[rt][ct][reg];
                ps += v * asv[ct]; pd += v * adv[ct];
            }
            #pragma unroll
            for (int o = 1; o < 16; o <<= 1) { ps += __shfl_xor(ps, o); pd += __shfl_xor(pd, o); }
            int grow = row0 + rt * 16 + q * 4 + reg;
            if (m16 == 0 && grow < NODES_REAL) {
                sv[grow] = ps; dv[grow] = pd;
                atomicMax(gmaxu, encmax(ps));
            }
        }
}

// ---------------- aggregation: one wave per dst, global-bound softmax ----------
__global__ __launch_bounds__(256)
void agg_kernel(const float* __restrict__ h2, const float* __restrict__ sv,
                const float* __restrict__ dv, const int* __restrict__ offs,
                const ushort_t* __restrict__ esrc, const float* __restrict__ bias,
                float* __restrict__ out, const uint_t* __restrict__ gmaxu) {
    int w = threadIdx.x >> 6, lane = threadIdx.x & 63;
    int i = blockIdx.x * 4 + w;
    int start = offs[i], end = offs[i + 1];
    float d_i = dv[i];
    float gm = decmax(*gmaxu) + d_i;       // upper bound on every incoming score
    float m = gm > 0.f ? gm : NEG * gm;    // leaky_relu monotone -> exact shift
    float ax = 0.f, ay = 0.f, exs = 0.f;
    for (int base = start; base < end; base += 64) {
        int cnt = min(64, end - base);
        int srci = (lane < cnt) ? (int)esrc[base + lane] : 0;
        float sc = sv[srci] + d_i;
        sc = sc > 0.f ? sc : NEG * sc;
        float ex = (lane < cnt) ? __expf(sc - m) : 0.f;
        exs += ex;
        if (cnt == 64) {
            #pragma unroll 4
            for (int j = 0; j < 64; ++j) {
                int   src = __shfl(srci, j);
                float e   = __shfl(ex, j);
                float2 hv = *(const float2*)&h2[(size_t)src * D + 2 * lane];
                ax += e * hv.x; ay += e * hv.y;
            }
        } else {
            for (int j = 0; j < cnt; ++j) {
                int   src = __shfl(srci, j);
                float e   = __shfl(ex, j);
                float2 hv = *(const float2*)&h2[(size_t)src * D + 2 * lane];
                ax += e * hv.x; ay += e * hv.y;
            }
        }
    }
    float scf = sv[i] + d_i; scf = scf > 0.f ? scf : NEG * scf;
    float exf = __expf(scf - m);
    float2 hv = *(const float2*)&h2[(size_t)i * D + 2 * lane];
    ax += exf * hv.x; ay += exf * hv.y;
    #pragma unroll
    for (int o = 1; o < 64; o <<= 1) exs += __shfl_xor(exs, o);
    float rd = 1.f / (exs + exf);
    float2 b2 = *(const float2*)&bias[2 * lane];
    float2 o2 = make_float2(fmaxf(ax * rd + b2.x, 0.f), fmaxf(ay * rd + b2.y, 0.f));
    *(float2*)&out[(size_t)i * D + 2 * lane] = o2;
}

// ---------------- launcher -----------------------------------------------------
extern "C" void kernel_launch(void* const* d_in, const int* in_sizes, int n_in,
                              void* d_out, int out_size, void* d_ws, size_t ws_size,
                              hipStream_t stream) {
    const float* x   = (const float*)d_in[0];
    const int*   ei  = (const int*)d_in[1];
    const float* Ws  = (const float*)d_in[2];
    const float* as_ = (const float*)d_in[3];
    const float* ad_ = (const float*)d_in[4];
    const float* bs  = (const float*)d_in[5];
    float* out = (float*)d_out;
    int Eh = in_sizes[1] / 2;                    // 1,280,000

    char* ws = (char*)d_ws;
    float*    h2     = (float*)ws;                        //  2,560,000
    float*    bufS   = (float*)(ws + 2560000);            //  2,560,000
    float*    sv     = (float*)(ws + 5120000);            //     20,000
    float*    dv     = (float*)(ws + 5140000);            //     20,000
    int*      counts = (int*)  (ws + 5160000);            //     20,000
    int*      offs   = (int*)  (ws + 5180000);            //     20,016
    ushort_t* rank16 = (ushort_t*)(ws + 5200016);         //  2,560,000
    ushort_t* esrc   = (ushort_t*)(ws + 7760016);         //  2,560,000
    ushort_t* Wt     = (ushort_t*)(ws + 10320016);        //    208,896
    uint_t*   gmaxu  = (uint_t*)(ws + 10528912);          //         12

    zero_kernel<<<(NODES_REAL + 255) / 256, 256, 0, stream>>>(counts, gmaxu);
    rank_kernel<<<(Eh + 255) / 256, 256, 0, stream>>>(ei, counts, rank16, Eh);
    scan_kernel<<<1, 1024, 0, stream>>>(counts, offs);
    scatter_det<<<(Eh + 255) / 256, 256, 0, stream>>>(ei, offs, rank16, esrc, Eh);
    wsplit_kernel<<<24, 256, 0, stream>>>(Ws, Wt);

    // rows >= 5000: fused 3-layer MLP, one HBM pass
    mlp3_kernel<<<(NODES_TOTAL - NODES_REAL + 127) / 128, 256, 0, stream>>>(x, Wt, bs, out);

    // rows < 5000: per-layer GAT pipeline
    for (int l = 0; l < 3; ++l) {
        const float* hin = (l == 0) ? x : bufS;
        float* hout = (l == 2) ? out : bufS;
        gsmall_kernel<<<(NODES_REAL + 127) / 128, 256, 0, stream>>>(
            hin, Wt + (size_t)l * WT_L, as_ + l * D, ad_ + l * D, h2, sv, dv, gmaxu + l);
        agg_kernel<<<(NODES_REAL + 3) / 4, 256, 0, stream>>>(
            h2, sv, dv, offs, esrc, bs + l * D, hout, gmaxu + l);
    }
}